// Round 3
// baseline (7333.663 us; speedup 1.0000x reference)
//
#include <hip/hip_runtime.h>
#include <hip/hip_bf16.h>
#include <cstdint>

typedef __bf16 bf16_t;
typedef __bf16 bf16x4 __attribute__((ext_vector_type(4)));
typedef __bf16 bf16x8 __attribute__((ext_vector_type(8)));
typedef float f32x4 __attribute__((ext_vector_type(4)));

#define BATCH 4096
#define DIN   1024
#define HID   2048
#define DOUT  1000
#define NITER 50
#define LR    0.001f

#define BM 128
#define BN 128
#define BK 32

// async global -> LDS, 16 B per lane. LDS dest is wave-uniform base + lane*16.
#define GLDS(g, l)                                                        \
    __builtin_amdgcn_global_load_lds(                                     \
        (const __attribute__((address_space(1))) void*)(g),               \
        (__attribute__((address_space(3))) void*)(l), 16, 0, 0)

// ---------------------------------------------------------------------------
// gemm_bt: C[M,N] = A[M,K] @ Bt[N,K]^T, row-major, bf16 in, f32 acc.
// 512 threads = 8 waves (2 rows x 4 cols); wave tile 64x32 -> acc[4][2].
// Double-buffered LDS; prefetch of tile t+1 is issued BEFORE the ds_read+MFMA
// of tile t; ONE barrier per K-step (its implicit vmcnt(0) drain lands after
// a full compute phase of overlap).  Manually 2-unrolled for static buffer
// indices.
// EPI: 2  = h-update epilogue (B1 = W_rec)
//      3  = y-update epilogue (B1 = W_out padded)
//      13 = merged: blockIdx.y<8 -> role 3 (B2 = W_out), else role 1
//           (B1 = W_rec^T, produces e_x for the NEXT iteration)
// role 1: e_x = x - sigmoid(z + bias_gen); store bf16; energy += e^2
// role 2: h_f32 += LR*z; h_bf16 = (bf16)h_f32
// role 3: cols<DOUT: e = y - (z + bias_out); y += LR*e; energy += e^2
// ---------------------------------------------------------------------------
template <int EPI>
__global__ __launch_bounds__(512) void gemm_bt(
    const bf16_t* __restrict__ A, const bf16_t* __restrict__ B1,
    const bf16_t* __restrict__ B2, int K,
    const float* __restrict__ xin, const float* __restrict__ bias_g,
    const float* __restrict__ bias_o,
    bf16_t* __restrict__ exout, float* __restrict__ hf, bf16_t* __restrict__ hb,
    float* __restrict__ yout, float* __restrict__ energy)
{
    __shared__ __align__(16) bf16_t sA[2][BM * BK];
    __shared__ __align__(16) bf16_t sB[2][BN * BK];

    const int t    = threadIdx.x;
    const int lane = t & 63;
    const int wave = t >> 6;        // 0..7
    const int wm   = wave >> 2;     // wave row (0..1) -> 64 rows
    const int wn   = wave & 3;      // wave col (0..3) -> 32 cols
    const int m0   = blockIdx.x * BM;
    const int lr   = lane & 15;        // fragment row/col within 16
    const int lkb  = (lane >> 4) * 8;  // fragment k offset (8 contiguous)

    int role = EPI;
    int n0   = blockIdx.y * BN;
    const bf16_t* Bt = B1;
    if constexpr (EPI == 13) {
        if ((int)blockIdx.y < 8) {            // role 3: W_out cols 0..1023
            role = 3; Bt = B2;
        } else {                              // role 1: W_rec^T cols 0..1023
            role = 1; Bt = B1; n0 = ((int)blockIdx.y - 8) * BN;
        }
    }

    f32x4 acc[4][2] = {};

    // staging: lane l of wave w -> tile row w*16 + l/4, col chunk (l&3)*8
    const int srow = wave * 16 + (lane >> 2);
    const int scol = (lane & 3) * 8;
    const bf16_t* gA = A  + (int64_t)(m0 + srow) * K + scol;
    const bf16_t* gB = Bt + (int64_t)(n0 + srow) * K + scol;
    bf16_t* const lA0 = &sA[0][wave * 512];
    bf16_t* const lB0 = &sB[0][wave * 512];
    bf16_t* const lA1 = &sA[1][wave * 512];
    bf16_t* const lB1 = &sB[1][wave * 512];

#define COMPUTE(buf)                                                          \
    do {                                                                      \
        bf16x8 af[4], bfr[2];                                                 \
        _Pragma("unroll")                                                     \
        for (int mi = 0; mi < 4; ++mi)                                        \
            af[mi] = *reinterpret_cast<const bf16x8*>(                        \
                &sA[buf][(wm * 64 + mi * 16 + lr) * BK + lkb]);               \
        _Pragma("unroll")                                                     \
        for (int ni = 0; ni < 2; ++ni)                                        \
            bfr[ni] = *reinterpret_cast<const bf16x8*>(                       \
                &sB[buf][(wn * 32 + ni * 16 + lr) * BK + lkb]);               \
        _Pragma("unroll")                                                     \
        for (int mi = 0; mi < 4; ++mi)                                        \
            _Pragma("unroll")                                                 \
            for (int ni = 0; ni < 2; ++ni)                                    \
                acc[mi][ni] = __builtin_amdgcn_mfma_f32_16x16x32_bf16(        \
                    af[mi], bfr[ni], acc[mi][ni], 0, 0, 0);                   \
    } while (0)

    // prologue: stage tile 0 into buf0
    GLDS(gA, lA0);
    GLDS(gB, lB0);
    __syncthreads();

    const int nt = K / BK;                 // 32 or 64 (always even)
    for (int ts = 0; ts < nt; ts += 2) {
        // even step: prefetch tile ts+1 -> buf1, compute buf0
        {
            const int64_t k1 = (int64_t)(ts + 1) * BK;
            GLDS(gA + k1, lA1);
            GLDS(gB + k1, lB1);
            COMPUTE(0);
            __syncthreads();
        }
        // odd step: prefetch tile ts+2 -> buf0 (if any), compute buf1
        {
            if (ts + 2 < nt) {
                const int64_t k2 = (int64_t)(ts + 2) * BK;
                GLDS(gA + k2, lA0);
                GLDS(gB + k2, lB0);
            }
            COMPUTE(1);
            __syncthreads();
        }
    }
#undef COMPUTE

    // epilogue: C mapping col=lane&15, row=(lane>>4)*4+j
    float esum = 0.0f;
    const int prow = (lane >> 4) * 4;
#pragma unroll
    for (int mi = 0; mi < 4; ++mi) {
#pragma unroll
        for (int ni = 0; ni < 2; ++ni) {
            const int col = n0 + wn * 32 + ni * 16 + lr;
#pragma unroll
            for (int j = 0; j < 4; ++j) {
                const int row = m0 + wm * 64 + mi * 16 + prow + j;
                const float v = acc[mi][ni][j];
                if (role == 1) {
                    const float z  = v + bias_g[col];
                    const float xp = 1.0f / (1.0f + __expf(-z));
                    const float e  = xin[(int64_t)row * DIN + col] - xp;
                    exout[(int64_t)row * DIN + col] = (bf16_t)e;
                    esum += e * e;
                } else if (role == 2) {
                    const int64_t idx = (int64_t)row * HID + col;
                    const float nh = hf[idx] + LR * v;
                    hf[idx] = nh;
                    hb[idx] = (bf16_t)nh;
                } else {
                    if (col < DOUT) {
                        const int64_t idx = (int64_t)row * DOUT + col;
                        const float yp = v + bias_o[col];
                        const float yo = yout[idx];
                        const float e  = yo - yp;
                        yout[idx] = yo + LR * e;
                        esum += e * e;
                    }
                }
            }
        }
    }
    if constexpr (EPI != 2) {
        if (role != 2) {
#pragma unroll
            for (int off = 32; off; off >>= 1) esum += __shfl_down(esum, off, 64);
            if (lane == 0) atomicAdd(energy, esum);
        }
    }
}

// W_rec [HID][DIN] f32 -> bf16 copy + bf16 transpose [DIN][HID]
__global__ void conv_wrec(const float* __restrict__ W, bf16_t* __restrict__ Wb,
                          bf16_t* __restrict__ WbT)
{
    __shared__ float tile[32][33];
    const int tx = threadIdx.x & 31;
    const int ty = threadIdx.x >> 5; // 0..7
    const int c0 = blockIdx.x * 32;  // DIN
    const int r0 = blockIdx.y * 32;  // HID
#pragma unroll
    for (int rr = ty; rr < 32; rr += 8) {
        const float v = W[(int64_t)(r0 + rr) * DIN + c0 + tx];
        Wb[(int64_t)(r0 + rr) * DIN + c0 + tx] = (bf16_t)v;
        tile[rr][tx] = v;
    }
    __syncthreads();
#pragma unroll
    for (int rr = ty; rr < 32; rr += 8)
        WbT[(int64_t)(c0 + rr) * HID + r0 + tx] = (bf16_t)tile[tx][rr];
}

// W_out [DOUT][HID] f32 -> bf16 [1024][HID], rows >= DOUT zero-padded
__global__ void conv_wout(const float* __restrict__ W, bf16_t* __restrict__ Wb)
{
    const int i = blockIdx.x * 256 + threadIdx.x; // over 1024*2048
    const int r = i >> 11;
    const int c = i & 2047;
    Wb[i] = (r < DOUT) ? (bf16_t)W[(int64_t)r * HID + c] : (bf16_t)0.0f;
}

// iteration 0: h = 0 -> x_pred = 0.5 exactly; e_x = x - 0.5 (+ energy)
__global__ void ex0_kernel(const float* __restrict__ x, bf16_t* __restrict__ ex,
                           float* __restrict__ energy)
{
    __shared__ float red[4];
    const int t = threadIdx.x, lane = t & 63, wave = t >> 6;
    const int i = (blockIdx.x * 256 + t) * 4;
    const float4 v = *reinterpret_cast<const float4*>(&x[i]);
    const float e0 = v.x - 0.5f, e1 = v.y - 0.5f, e2 = v.z - 0.5f, e3 = v.w - 0.5f;
    bf16x4 o = {(bf16_t)e0, (bf16_t)e1, (bf16_t)e2, (bf16_t)e3};
    *reinterpret_cast<bf16x4*>(&ex[i]) = o;
    float esum = e0 * e0 + e1 * e1 + e2 * e2 + e3 * e3;
#pragma unroll
    for (int off = 32; off; off >>= 1) esum += __shfl_down(esum, off, 64);
    if (lane == 0) red[wave] = esum;
    __syncthreads();
    if (t == 0) atomicAdd(energy, red[0] + red[1] + red[2] + red[3]);
}

__global__ void finalize_kernel(const float* __restrict__ energy,
                                float* __restrict__ out)
{
    out[0] = energy[0] * (1.0f / ((float)BATCH * (float)NITER));
}

extern "C" void kernel_launch(void* const* d_in, const int* in_sizes, int n_in,
                              void* d_out, int out_size, void* d_ws, size_t ws_size,
                              hipStream_t stream)
{
    (void)in_sizes; (void)n_in; (void)out_size; (void)ws_size;
    const float* x        = (const float*)d_in[0];
    const float* W_rec    = (const float*)d_in[1];
    const float* W_out    = (const float*)d_in[2];
    const float* bias_out = (const float*)d_in[3];
    const float* bias_gen = (const float*)d_in[4];
    float* y = (float*)d_out; // [BATCH*DOUT] then [1] energy

    char* ws = (char*)d_ws;
    size_t off = 0;
    float* h_f32 = (float*)(ws + off);   off += (size_t)BATCH * HID * 4;  // 32 MB
    bf16_t* h_bf = (bf16_t*)(ws + off);  off += (size_t)BATCH * HID * 2;  // 16 MB
    bf16_t* ex_bf = (bf16_t*)(ws + off); off += (size_t)BATCH * DIN * 2;  //  8 MB
    bf16_t* wrec_bf = (bf16_t*)(ws + off);  off += (size_t)HID * DIN * 2; //  4 MB
    bf16_t* wrecT_bf = (bf16_t*)(ws + off); off += (size_t)HID * DIN * 2; //  4 MB
    bf16_t* wout_bf = (bf16_t*)(ws + off);  off += (size_t)1024 * HID * 2;//  4 MB
    float* energy = (float*)(ws + off);     off += 256;

    hipMemsetAsync(h_f32, 0, (size_t)BATCH * HID * 4, stream);
    hipMemsetAsync(y, 0, (size_t)BATCH * DOUT * 4, stream);
    hipMemsetAsync(energy, 0, 4, stream);

    conv_wrec<<<dim3(DIN / 32, HID / 32), 256, 0, stream>>>(W_rec, wrec_bf, wrecT_bf);
    conv_wout<<<(1024 * HID) / 256, 256, 0, stream>>>(W_out, wout_bf);

    const dim3 g2(BATCH / BM, HID / BN);    // 32 x 16  (h-update, K=DIN)
    const dim3 g13(BATCH / BM, 16);         // 32 x 16  (merged y-update + next e_x)
    const dim3 g3(BATCH / BM, 1024 / BN);   // 32 x 8   (final y-update)

    // iteration 0 e_x (h = 0 -> x_pred = 0.5 exactly)
    ex0_kernel<<<(BATCH * DIN) / 1024, 256, 0, stream>>>(x, ex_bf, energy);

    for (int it = 0; it < NITER; ++it) {
        gemm_bt<2><<<g2, 512, 0, stream>>>(ex_bf, wrec_bf, nullptr, DIN,
                                           nullptr, nullptr, nullptr,
                                           nullptr, h_f32, h_bf, nullptr, nullptr);
        if (it < NITER - 1)
            gemm_bt<13><<<g13, 512, 0, stream>>>(h_bf, wrecT_bf, wout_bf, HID,
                                                 x, bias_gen, bias_out,
                                                 ex_bf, nullptr, nullptr, y, energy);
        else
            gemm_bt<3><<<g3, 512, 0, stream>>>(h_bf, wout_bf, nullptr, HID,
                                               nullptr, nullptr, bias_out,
                                               nullptr, nullptr, nullptr, y, energy);
    }
    finalize_kernel<<<1, 1, 0, stream>>>(energy, y + (size_t)BATCH * DOUT);
}

// Round 4
// 4327.642 us; speedup vs baseline: 1.6946x; 1.6946x over previous
//
#include <hip/hip_runtime.h>
#include <hip/hip_bf16.h>
#include <cstdint>

typedef __bf16 bf16_t;
typedef __bf16 bf16x4 __attribute__((ext_vector_type(4)));
typedef __bf16 bf16x8 __attribute__((ext_vector_type(8)));
typedef float f32x4 __attribute__((ext_vector_type(4)));

#define BATCH 4096
#define DIN   1024
#define HID   2048
#define DOUT  1000
#define NITER 50
#define LR    0.001f

#define BM 128
#define BN 128
#define BK 32
#define NBUF 3

// async global -> LDS, 16 B per lane. LDS dest is wave-uniform base + lane*16.
#define GLDS(g, l)                                                        \
    __builtin_amdgcn_global_load_lds(                                     \
        (const __attribute__((address_space(1))) void*)(g),               \
        (__attribute__((address_space(3))) void*)(l), 16, 0, 0)

#define WAITVM(N) asm volatile("s_waitcnt vmcnt(" #N ")" ::: "memory")
#define BAR()     __builtin_amdgcn_s_barrier()
#define SCHEDB()  __builtin_amdgcn_sched_barrier(0)

// ---------------------------------------------------------------------------
// gemm_bt: C[M,N] = A[M,K] @ Bt[N,K]^T, row-major, bf16 in, f32 acc.
// 512 threads = 8 waves (2x4); wave tile 64x32 -> acc[4][2].
// K-loop: triple-buffered LDS, depth-3 pipeline with COUNTED vmcnt (T4):
// tiles t+1,t+2 stay in flight across raw s_barriers; never drain to 0 in
// the main loop (vmcnt(4) steady, 4->2->0 tail).
// EPI: 2  = h-update (B1 = W_rec)
//      3  = y-update (B1 = W_out padded)
//      13 = merged: blockIdx.y<8 -> role 3 (B2=W_out), else role 1 (B1=W_rec^T)
// role 1: e_x = x - sigmoid(z + bias_gen); store bf16; energy += e^2
// role 2: h_f32 += LR*z; h_bf16 = (bf16)h_f32
// role 3: cols<DOUT: e = y - (z + bias_out); y += LR*e; energy += e^2
// ---------------------------------------------------------------------------
template <int EPI>
__global__ __launch_bounds__(512) void gemm_bt(
    const bf16_t* __restrict__ A, const bf16_t* __restrict__ B1,
    const bf16_t* __restrict__ B2, int K,
    const float* __restrict__ xin, const float* __restrict__ bias_g,
    const float* __restrict__ bias_o,
    bf16_t* __restrict__ exout, float* __restrict__ hf, bf16_t* __restrict__ hb,
    float* __restrict__ yout, float* __restrict__ energy)
{
    __shared__ __align__(16) bf16_t sA[NBUF][BM * BK];
    __shared__ __align__(16) bf16_t sB[NBUF][BN * BK];
    __shared__ float red[8];

    const int t    = threadIdx.x;
    const int lane = t & 63;
    const int wave = t >> 6;        // 0..7
    const int wm   = wave >> 2;     // wave row (0..1) -> 64 rows
    const int wn   = wave & 3;      // wave col (0..3) -> 32 cols
    const int m0   = blockIdx.x * BM;
    const int lr   = lane & 15;        // fragment row/col within 16
    const int lkb  = (lane >> 4) * 8;  // fragment k offset (8 contiguous)

    int role = EPI;
    int n0   = blockIdx.y * BN;
    const bf16_t* Bt = B1;
    if constexpr (EPI == 13) {
        if ((int)blockIdx.y < 8) {            // role 3: W_out cols 0..1023
            role = 3; Bt = B2;
        } else {                              // role 1: W_rec^T cols 0..1023
            role = 1; Bt = B1; n0 = ((int)blockIdx.y - 8) * BN;
        }
    }

    f32x4 acc[4][2] = {};

    // staging: lane l of wave w -> tile row w*16 + l/4, col chunk (l&3)*8
    const int srow = wave * 16 + (lane >> 2);
    const int scol = (lane & 3) * 8;
    const bf16_t* gA = A  + (int64_t)(m0 + srow) * K + scol;
    const bf16_t* gB = Bt + (int64_t)(n0 + srow) * K + scol;

    auto stage = [&](int tile, int buf) {
        const int64_t ko = (int64_t)tile * BK;
        GLDS(gA + ko, &sA[buf][wave * 512]);
        GLDS(gB + ko, &sB[buf][wave * 512]);
    };

    auto compute = [&](int buf) {
        bf16x8 af[4], bfr[2];
#pragma unroll
        for (int mi = 0; mi < 4; ++mi)
            af[mi] = *reinterpret_cast<const bf16x8*>(
                &sA[buf][(wm * 64 + mi * 16 + lr) * BK + lkb]);
#pragma unroll
        for (int ni = 0; ni < 2; ++ni)
            bfr[ni] = *reinterpret_cast<const bf16x8*>(
                &sB[buf][(wn * 32 + ni * 16 + lr) * BK + lkb]);
#pragma unroll
        for (int mi = 0; mi < 4; ++mi)
#pragma unroll
            for (int ni = 0; ni < 2; ++ni)
                acc[mi][ni] = __builtin_amdgcn_mfma_f32_16x16x32_bf16(
                    af[mi], bfr[ni], acc[mi][ni], 0, 0, 0);
    };

    const int nt = K / BK;                 // 32 or 64
    // prologue: tiles 0,1,2 in flight (6 loads)
    stage(0, 0);
    stage(1, 1);
    stage(2, 2);

    for (int ts = 0; ts < nt - 3; ++ts) {
        WAITVM(4);               // tile ts done; ts+1, ts+2 still flying
        BAR();                   // all waves' slices of tile ts visible
        SCHEDB();
        compute(ts % 3);
        BAR();                   // all waves done reading buf ts%3
        stage(ts + 3, ts % 3);   // restage it; never drain vmcnt to 0
    }
    WAITVM(4); BAR(); SCHEDB(); compute((nt - 3) % 3);
    WAITVM(2); BAR(); SCHEDB(); compute((nt - 2) % 3);
    WAITVM(0); BAR(); SCHEDB(); compute((nt - 1) % 3);

    // epilogue: C mapping col=lane&15, row=(lane>>4)*4+j
    float esum = 0.0f;
    const int prow = (lane >> 4) * 4;
#pragma unroll
    for (int mi = 0; mi < 4; ++mi) {
#pragma unroll
        for (int ni = 0; ni < 2; ++ni) {
            const int col = n0 + wn * 32 + ni * 16 + lr;
#pragma unroll
            for (int j = 0; j < 4; ++j) {
                const int row = m0 + wm * 64 + mi * 16 + prow + j;
                const float v = acc[mi][ni][j];
                if (role == 1) {
                    const float z  = v + bias_g[col];
                    const float xp = 1.0f / (1.0f + __expf(-z));
                    const float e  = xin[(int64_t)row * DIN + col] - xp;
                    exout[(int64_t)row * DIN + col] = (bf16_t)e;
                    esum += e * e;
                } else if (role == 2) {
                    const int64_t idx = (int64_t)row * HID + col;
                    const float nh = hf[idx] + LR * v;
                    hf[idx] = nh;
                    hb[idx] = (bf16_t)nh;
                } else {
                    if (col < DOUT) {
                        const int64_t idx = (int64_t)row * DOUT + col;
                        const float yp = v + bias_o[col];
                        const float yo = yout[idx];
                        const float e  = yo - yp;
                        yout[idx] = yo + LR * e;
                        esum += e * e;
                    }
                }
            }
        }
    }
    if constexpr (EPI != 2) {
#pragma unroll
        for (int off = 32; off; off >>= 1) esum += __shfl_down(esum, off, 64);
        if (lane == 0) red[wave] = esum;
        __syncthreads();
        if (t == 0) {
            float s = 0.0f;
#pragma unroll
            for (int w = 0; w < 8; ++w) s += red[w];
            atomicAdd(energy, s);
        }
    }
}

// W_rec [HID][DIN] f32 -> bf16 copy + bf16 transpose [DIN][HID]
__global__ void conv_wrec(const float* __restrict__ W, bf16_t* __restrict__ Wb,
                          bf16_t* __restrict__ WbT)
{
    __shared__ float tile[32][33];
    const int tx = threadIdx.x & 31;
    const int ty = threadIdx.x >> 5; // 0..7
    const int c0 = blockIdx.x * 32;  // DIN
    const int r0 = blockIdx.y * 32;  // HID
#pragma unroll
    for (int rr = ty; rr < 32; rr += 8) {
        const float v = W[(int64_t)(r0 + rr) * DIN + c0 + tx];
        Wb[(int64_t)(r0 + rr) * DIN + c0 + tx] = (bf16_t)v;
        tile[rr][tx] = v;
    }
    __syncthreads();
#pragma unroll
    for (int rr = ty; rr < 32; rr += 8)
        WbT[(int64_t)(c0 + rr) * HID + r0 + tx] = (bf16_t)tile[tx][rr];
}

// W_out [DOUT][HID] f32 -> bf16 [1024][HID], rows >= DOUT zero-padded
__global__ void conv_wout(const float* __restrict__ W, bf16_t* __restrict__ Wb)
{
    const int i = blockIdx.x * 256 + threadIdx.x; // over 1024*2048
    const int r = i >> 11;
    const int c = i & 2047;
    Wb[i] = (r < DOUT) ? (bf16_t)W[(int64_t)r * HID + c] : (bf16_t)0.0f;
}

// iteration 0: h = 0 -> x_pred = 0.5 exactly; e_x = x - 0.5 (+ energy)
__global__ void ex0_kernel(const float* __restrict__ x, bf16_t* __restrict__ ex,
                           float* __restrict__ energy)
{
    __shared__ float red[4];
    const int t = threadIdx.x, lane = t & 63, wave = t >> 6;
    const int i = (blockIdx.x * 256 + t) * 4;
    const float4 v = *reinterpret_cast<const float4*>(&x[i]);
    const float e0 = v.x - 0.5f, e1 = v.y - 0.5f, e2 = v.z - 0.5f, e3 = v.w - 0.5f;
    bf16x4 o = {(bf16_t)e0, (bf16_t)e1, (bf16_t)e2, (bf16_t)e3};
    *reinterpret_cast<bf16x4*>(&ex[i]) = o;
    float esum = e0 * e0 + e1 * e1 + e2 * e2 + e3 * e3;
#pragma unroll
    for (int off = 32; off; off >>= 1) esum += __shfl_down(esum, off, 64);
    if (lane == 0) red[wave] = esum;
    __syncthreads();
    if (t == 0) atomicAdd(energy, red[0] + red[1] + red[2] + red[3]);
}

__global__ void finalize_kernel(const float* __restrict__ energy,
                                float* __restrict__ out)
{
    out[0] = energy[0] * (1.0f / ((float)BATCH * (float)NITER));
}

extern "C" void kernel_launch(void* const* d_in, const int* in_sizes, int n_in,
                              void* d_out, int out_size, void* d_ws, size_t ws_size,
                              hipStream_t stream)
{
    (void)in_sizes; (void)n_in; (void)out_size; (void)ws_size;
    const float* x        = (const float*)d_in[0];
    const float* W_rec    = (const float*)d_in[1];
    const float* W_out    = (const float*)d_in[2];
    const float* bias_out = (const float*)d_in[3];
    const float* bias_gen = (const float*)d_in[4];
    float* y = (float*)d_out; // [BATCH*DOUT] then [1] energy

    char* ws = (char*)d_ws;
    size_t off = 0;
    float* h_f32 = (float*)(ws + off);   off += (size_t)BATCH * HID * 4;  // 32 MB
    bf16_t* h_bf = (bf16_t*)(ws + off);  off += (size_t)BATCH * HID * 2;  // 16 MB
    bf16_t* ex_bf = (bf16_t*)(ws + off); off += (size_t)BATCH * DIN * 2;  //  8 MB
    bf16_t* wrec_bf = (bf16_t*)(ws + off);  off += (size_t)HID * DIN * 2; //  4 MB
    bf16_t* wrecT_bf = (bf16_t*)(ws + off); off += (size_t)HID * DIN * 2; //  4 MB
    bf16_t* wout_bf = (bf16_t*)(ws + off);  off += (size_t)1024 * HID * 2;//  4 MB
    float* energy = (float*)(ws + off);     off += 256;

    hipMemsetAsync(h_f32, 0, (size_t)BATCH * HID * 4, stream);
    hipMemsetAsync(y, 0, (size_t)BATCH * DOUT * 4, stream);
    hipMemsetAsync(energy, 0, 4, stream);

    conv_wrec<<<dim3(DIN / 32, HID / 32), 256, 0, stream>>>(W_rec, wrec_bf, wrecT_bf);
    conv_wout<<<(1024 * HID) / 256, 256, 0, stream>>>(W_out, wout_bf);

    const dim3 g2(BATCH / BM, HID / BN);    // 32 x 16  (h-update, K=DIN)
    const dim3 g13(BATCH / BM, 16);         // 32 x 16  (merged y-update + next e_x)
    const dim3 g3(BATCH / BM, 1024 / BN);   // 32 x 8   (final y-update)

    // iteration 0 e_x (h = 0 -> x_pred = 0.5 exactly)
    ex0_kernel<<<(BATCH * DIN) / 1024, 256, 0, stream>>>(x, ex_bf, energy);

    for (int it = 0; it < NITER; ++it) {
        gemm_bt<2><<<g2, 512, 0, stream>>>(ex_bf, wrec_bf, nullptr, DIN,
                                           nullptr, nullptr, nullptr,
                                           nullptr, h_f32, h_bf, nullptr, nullptr);
        if (it < NITER - 1)
            gemm_bt<13><<<g13, 512, 0, stream>>>(h_bf, wrecT_bf, wout_bf, HID,
                                                 x, bias_gen, bias_out,
                                                 ex_bf, nullptr, nullptr, y, energy);
        else
            gemm_bt<3><<<g3, 512, 0, stream>>>(h_bf, wout_bf, nullptr, HID,
                                               nullptr, nullptr, bias_out,
                                               nullptr, nullptr, nullptr, y, energy);
    }
    finalize_kernel<<<1, 1, 0, stream>>>(energy, y + (size_t)BATCH * DOUT);
}